// Round 1
// baseline (480.159 us; speedup 1.0000x reference)
//
#include <hip/hip_runtime.h>
#include <stdint.h>

#define NN 8192
#define DD 256

typedef __attribute__((ext_vector_type(8))) short short8;
typedef __attribute__((ext_vector_type(4))) float f32x4;

typedef const uint32_t __attribute__((address_space(1)))* gbl_ptr_t;
typedef uint32_t __attribute__((address_space(3)))* lds_ptr_t;

__device__ __forceinline__ void gl_lds16(const void* g, const void* l) {
    // async global->LDS, 16B per lane; LDS dest = wave-uniform base + lane*16
    __builtin_amdgcn_global_load_lds((gbl_ptr_t)(uintptr_t)g,
                                     (lds_ptr_t)(uintptr_t)l, 16, 0, 0);
}

__device__ __forceinline__ unsigned short f32_to_bf16(float f) {
    uint32_t u = __float_as_uint(f);
    u += 0x7fff + ((u >> 16) & 1);   // RNE
    return (unsigned short)(u >> 16);
}
__device__ __forceinline__ float bf16_to_f32(unsigned short h) {
    return __uint_as_float(((uint32_t)h) << 16);
}

// ---------------------------------------------------------------------------
// prep: one 256-thread block per row r.
//  - hi/lo bf16 split of x, stored PRE-SWIZZLED: within each 64-col K-tile,
//    16B-group g goes to slot g ^ (r&7).  Then a linear global_load_lds stage
//    + XOR-swizzled ds_read is bank-conflict-free (both-sides-or-neither).
//  - sq[r] = sum x^2 (fp32), denom[r] = 0 (atomicAdd target; ws is poisoned).
// ---------------------------------------------------------------------------
__global__ void prep_kernel(const float* __restrict__ x,
                            unsigned short* __restrict__ hi,
                            unsigned short* __restrict__ lo,
                            float* __restrict__ sq,
                            float* __restrict__ denom) {
    const int r = blockIdx.x;
    const int t = threadIdx.x;                 // 0..255 = column
    float v = x[(size_t)r * DD + t];
    unsigned short h = f32_to_bf16(v);
    unsigned short l = f32_to_bf16(v - bf16_to_f32(h));
    int csw = (t & ~63) | ((((t >> 3) & 7) ^ (r & 7)) << 3) | (t & 7);
    hi[(size_t)r * DD + csw] = h;
    lo[(size_t)r * DD + csw] = l;

    float s = v * v;
    #pragma unroll
    for (int m = 32; m >= 1; m >>= 1) s += __shfl_xor(s, m, 64);
    __shared__ float ws[4];
    if ((t & 63) == 0) ws[t >> 6] = s;
    __syncthreads();
    if (t == 0) {
        sq[r] = ws[0] + ws[1] + ws[2] + ws[3];
        denom[r] = 0.0f;
    }
}

// ---------------------------------------------------------------------------
// dist: 128x128 output tile per block, 4 waves in 2x2, each wave 64x64 via
// 4x4 fragments of mfma_f32_16x16x32_bf16.  Split product: hihi+hilo+lohi.
// Epilogue: dist = sqrt(max(sq_i+sq_j-2dot,0)), store + row-sum atomicAdd.
// ---------------------------------------------------------------------------
__launch_bounds__(256, 2)
__global__ void dist_kernel(const unsigned short* __restrict__ hi,
                            const unsigned short* __restrict__ lo,
                            const float* __restrict__ sq,
                            float* __restrict__ out,
                            float* __restrict__ denom) {
    // 4 tiles of [128 rows][64 cols] bf16, 16 KB each = 64 KB
    __shared__ __align__(16) unsigned short lds[4 * 128 * 64];
    unsigned short* ldsAhi = lds;
    unsigned short* ldsAlo = lds + 8192;
    unsigned short* ldsBhi = lds + 16384;
    unsigned short* ldsBlo = lds + 24576;

    const int tid  = threadIdx.x;
    const int lane = tid & 63;
    const int wid  = tid >> 6;
    const int wm = wid >> 1, wn = wid & 1;     // 2x2 wave grid
    const int l15 = lane & 15, lk = lane >> 4; // frag row/col, K-group

    const int row0 = blockIdx.y * 128;
    const int col0 = blockIdx.x * 128;

    f32x4 acc[4][4];
    #pragma unroll
    for (int a = 0; a < 4; ++a)
        #pragma unroll
        for (int b = 0; b < 4; ++b) acc[a][b] = (f32x4){0.f, 0.f, 0.f, 0.f};

    // prefetch squared norms (L2-hot, prep already done)
    float rsq[4][4], csq[4];
    #pragma unroll
    for (int fm = 0; fm < 4; ++fm)
        #pragma unroll
        for (int r = 0; r < 4; ++r)
            rsq[fm][r] = sq[row0 + wm * 64 + fm * 16 + lk * 4 + r];
    #pragma unroll
    for (int fn = 0; fn < 4; ++fn)
        csq[fn] = sq[col0 + wn * 64 + fn * 16 + l15];

    // K loop: 4 tiles of BK=64 (K=256 total)
    for (int kt = 0; kt < 4; ++kt) {
        // ---- stage 4 tiles, linear LDS, 16B/lane x 4 calls x 256 thr ----
        #pragma unroll
        for (int c = 0; c < 4; ++c) {
            int lin  = c * 256 + tid;          // 0..1023 16B-chunks
            int row  = lin >> 3;               // 8 chunks per 128B row
            int col8 = lin & 7;
            size_t goffA = (size_t)(row0 + row) * DD + kt * 64 + col8 * 8;
            size_t goffB = (size_t)(col0 + row) * DD + kt * 64 + col8 * 8;
            size_t lbyte = (size_t)(c * 256 + wid * 64) * 16; // wave-uniform
            gl_lds16(hi + goffA, (const char*)ldsAhi + lbyte);
            gl_lds16(lo + goffA, (const char*)ldsAlo + lbyte);
            gl_lds16(hi + goffB, (const char*)ldsBhi + lbyte);
            gl_lds16(lo + goffB, (const char*)ldsBlo + lbyte);
        }
        __syncthreads();   // compiler drains vmcnt before s_barrier

        #pragma unroll
        for (int ks = 0; ks < 2; ++ks) {
            short8 ah[4], al[4], bh[4], bl[4];
            #pragma unroll
            for (int fm = 0; fm < 4; ++fm) {
                int row = wm * 64 + fm * 16 + l15;
                int cb  = (ks * 64 + lk * 16) ^ ((row & 7) << 4); // XOR swizzle
                int off = row * 64 + (cb >> 1);
                ah[fm] = *(const short8*)(ldsAhi + off);
                al[fm] = *(const short8*)(ldsAlo + off);
            }
            #pragma unroll
            for (int fn = 0; fn < 4; ++fn) {
                int row = wn * 64 + fn * 16 + l15;
                int cb  = (ks * 64 + lk * 16) ^ ((row & 7) << 4);
                int off = row * 64 + (cb >> 1);
                bh[fn] = *(const short8*)(ldsBhi + off);
                bl[fn] = *(const short8*)(ldsBlo + off);
            }
            #pragma unroll
            for (int fm = 0; fm < 4; ++fm)
                #pragma unroll
                for (int fn = 0; fn < 4; ++fn) {
                    acc[fm][fn] = __builtin_amdgcn_mfma_f32_16x16x32_bf16(
                        ah[fm], bh[fn], acc[fm][fn], 0, 0, 0);
                    acc[fm][fn] = __builtin_amdgcn_mfma_f32_16x16x32_bf16(
                        ah[fm], bl[fn], acc[fm][fn], 0, 0, 0);
                    acc[fm][fn] = __builtin_amdgcn_mfma_f32_16x16x32_bf16(
                        al[fm], bh[fn], acc[fm][fn], 0, 0, 0);
                }
        }
        __syncthreads();   // protect LDS before next stage
    }

    // ---- epilogue: dist, store, row partial sums ----
    float rp[4][4];
    #pragma unroll
    for (int a = 0; a < 4; ++a)
        #pragma unroll
        for (int b = 0; b < 4; ++b) rp[a][b] = 0.f;

    #pragma unroll
    for (int fm = 0; fm < 4; ++fm) {
        #pragma unroll
        for (int fn = 0; fn < 4; ++fn) {
            #pragma unroll
            for (int r = 0; r < 4; ++r) {
                float dot = acc[fm][fn][r];
                float sqd = rsq[fm][r] + csq[fn] - 2.0f * dot;
                sqd = fmaxf(sqd, 0.0f);
                float d = sqrtf(sqd);           // sqrt(0)=0 matches reference
                int grow = row0 + wm * 64 + fm * 16 + lk * 4 + r;
                int gcol = col0 + wn * 64 + fn * 16 + l15;
                out[(size_t)grow * NN + gcol] = d;
                rp[fm][r] += d;
            }
        }
    }
    // reduce across the 16 lanes (= 16 cols) of each quarter-wave group
    #pragma unroll
    for (int fm = 0; fm < 4; ++fm)
        #pragma unroll
        for (int r = 0; r < 4; ++r) {
            float v = rp[fm][r];
            v += __shfl_xor(v, 1, 64);
            v += __shfl_xor(v, 2, 64);
            v += __shfl_xor(v, 4, 64);
            v += __shfl_xor(v, 8, 64);
            if (l15 == 0)
                atomicAdd(&denom[row0 + wm * 64 + fm * 16 + lk * 4 + r], v);
        }
}

// ---------------------------------------------------------------------------
// normalize: out[i][j] /= denom[i], float4 grid-stride
// ---------------------------------------------------------------------------
__global__ void norm_kernel(float* __restrict__ out,
                            const float* __restrict__ denom) {
    const int total = NN * (NN / 4);           // 16M float4
    float4* o4 = reinterpret_cast<float4*>(out);
    for (int i = blockIdx.x * blockDim.x + threadIdx.x; i < total;
         i += gridDim.x * blockDim.x) {
        int row = i >> 11;                     // 2048 float4 per row
        float inv = 1.0f / denom[row];
        float4 v = o4[i];
        v.x *= inv; v.y *= inv; v.z *= inv; v.w *= inv;
        o4[i] = v;
    }
}

extern "C" void kernel_launch(void* const* d_in, const int* in_sizes, int n_in,
                              void* d_out, int out_size, void* d_ws, size_t ws_size,
                              hipStream_t stream) {
    const float* x = (const float*)d_in[0];
    float* out = (float*)d_out;
    char* ws = (char*)d_ws;
    unsigned short* hi = (unsigned short*)ws;                          // 4 MB
    unsigned short* lo = (unsigned short*)(ws + (size_t)NN * DD * 2);  // 4 MB
    float* sq    = (float*)(ws + (size_t)NN * DD * 4);                 // 32 KB
    float* denom = (float*)(ws + (size_t)NN * DD * 4 + NN * 4);        // 32 KB

    prep_kernel<<<NN, 256, 0, stream>>>(x, hi, lo, sq, denom);
    dim3 g(NN / 128, NN / 128);
    dist_kernel<<<g, 256, 0, stream>>>(hi, lo, sq, out, denom);
    norm_kernel<<<2048, 256, 0, stream>>>(out, denom);
}

// Round 3
// 426.632 us; speedup vs baseline: 1.1255x; 1.1255x over previous
//
#include <hip/hip_runtime.h>
#include <stdint.h>

#define NN 8192
#define DD 256

typedef __attribute__((ext_vector_type(8))) short short8;
typedef __attribute__((ext_vector_type(4))) float f32x4;

typedef const uint32_t __attribute__((address_space(1)))* gbl_ptr_t;
typedef uint32_t __attribute__((address_space(3)))* lds_ptr_t;

__device__ __forceinline__ void gl_lds16(const void* g, const void* l) {
    __builtin_amdgcn_global_load_lds((gbl_ptr_t)(uintptr_t)g,
                                     (lds_ptr_t)(uintptr_t)l, 16, 0, 0);
}

__device__ __forceinline__ unsigned short f32_to_bf16(float f) {
    uint32_t u = __float_as_uint(f);
    u += 0x7fff + ((u >> 16) & 1);   // RNE
    return (unsigned short)(u >> 16);
}
__device__ __forceinline__ float bf16_to_f32(unsigned short h) {
    return __uint_as_float(((uint32_t)h) << 16);
}

// ---------------------------------------------------------------------------
// prep: hi/lo bf16 split stored PRE-SWIZZLED (rule #21: linear gl_lds dest +
// inverse-swizzled source + XOR on ds_read), sq[r], denom[r]=0.
// ---------------------------------------------------------------------------
__global__ void prep_kernel(const float* __restrict__ x,
                            unsigned short* __restrict__ hi,
                            unsigned short* __restrict__ lo,
                            float* __restrict__ sq,
                            float* __restrict__ denom) {
    const int r = blockIdx.x;
    const int t = threadIdx.x;                 // 0..255 = column
    float v = x[(size_t)r * DD + t];
    unsigned short h = f32_to_bf16(v);
    unsigned short l = f32_to_bf16(v - bf16_to_f32(h));
    int csw = (t & ~63) | ((((t >> 3) & 7) ^ (r & 7)) << 3) | (t & 7);
    hi[(size_t)r * DD + csw] = h;
    lo[(size_t)r * DD + csw] = l;

    float s = v * v;
    #pragma unroll
    for (int m = 32; m >= 1; m >>= 1) s += __shfl_xor(s, m, 64);
    __shared__ float ws[4];
    if ((t & 63) == 0) ws[t >> 6] = s;
    __syncthreads();
    if (t == 0) {
        sq[r] = ws[0] + ws[1] + ws[2] + ws[3];
        denom[r] = 0.0f;
    }
}

// ---------------------------------------------------------------------------
// dist: UPPER-TRIANGLE tiles only (2080 blocks).  128x128 tile, 4 waves 2x2,
// each wave 4x4 frags of mfma_f32_16x16x32_bf16, split product hh+hl+lh.
// Epilogue: direct tile write + row sums; off-diag: col sums + LDS-transposed
// mirror-tile write.
// ---------------------------------------------------------------------------
__launch_bounds__(256, 2)
__global__ void dist_kernel(const unsigned short* __restrict__ hi,
                            const unsigned short* __restrict__ lo,
                            const float* __restrict__ sq,
                            float* __restrict__ out,
                            float* __restrict__ denom) {
    __shared__ __align__(16) unsigned short lds[4 * 128 * 64];  // 64 KB
    unsigned short* ldsAhi = lds;
    unsigned short* ldsAlo = lds + 8192;
    unsigned short* ldsBhi = lds + 16384;
    unsigned short* ldsBlo = lds + 24576;

    const int tid  = threadIdx.x;
    const int lane = tid & 63;
    const int wid  = tid >> 6;
    const int wm = wid >> 1, wn = wid & 1;
    const int l15 = lane & 15, lk = lane >> 4;

    // triangular decode: block -> (bi, bj), bj >= bi
    int t = blockIdx.x, bi = 0;
    while (t >= 64 - bi) { t -= 64 - bi; ++bi; }
    const int bj = bi + t;
    const int row0 = bi * 128;
    const int col0 = bj * 128;
    const bool offdiag = (bj > bi);

    f32x4 acc[4][4];
    #pragma unroll
    for (int a = 0; a < 4; ++a)
        #pragma unroll
        for (int b = 0; b < 4; ++b) acc[a][b] = (f32x4){0.f, 0.f, 0.f, 0.f};

    float rsq[4][4], csq[4];
    #pragma unroll
    for (int fm = 0; fm < 4; ++fm)
        #pragma unroll
        for (int r = 0; r < 4; ++r)
            rsq[fm][r] = sq[row0 + wm * 64 + fm * 16 + lk * 4 + r];
    #pragma unroll
    for (int fn = 0; fn < 4; ++fn)
        csq[fn] = sq[col0 + wn * 64 + fn * 16 + l15];

    for (int kt = 0; kt < 4; ++kt) {
        #pragma unroll
        for (int c = 0; c < 4; ++c) {
            int lin  = c * 256 + tid;
            int row  = lin >> 3;
            int col8 = lin & 7;
            size_t goffA = (size_t)(row0 + row) * DD + kt * 64 + col8 * 8;
            size_t goffB = (size_t)(col0 + row) * DD + kt * 64 + col8 * 8;
            size_t lbyte = (size_t)(c * 256 + wid * 64) * 16;
            gl_lds16(hi + goffA, (const char*)ldsAhi + lbyte);
            gl_lds16(lo + goffA, (const char*)ldsAlo + lbyte);
            gl_lds16(hi + goffB, (const char*)ldsBhi + lbyte);
            gl_lds16(lo + goffB, (const char*)ldsBlo + lbyte);
        }
        __syncthreads();

        #pragma unroll
        for (int ks = 0; ks < 2; ++ks) {
            short8 ah[4], al[4], bh[4], bl[4];
            #pragma unroll
            for (int fm = 0; fm < 4; ++fm) {
                int row = wm * 64 + fm * 16 + l15;
                int cb  = (ks * 64 + lk * 16) ^ ((row & 7) << 4);
                int off = row * 64 + (cb >> 1);
                ah[fm] = *(const short8*)(ldsAhi + off);
                al[fm] = *(const short8*)(ldsAlo + off);
            }
            #pragma unroll
            for (int fn = 0; fn < 4; ++fn) {
                int row = wn * 64 + fn * 16 + l15;
                int cb  = (ks * 64 + lk * 16) ^ ((row & 7) << 4);
                int off = row * 64 + (cb >> 1);
                bh[fn] = *(const short8*)(ldsBhi + off);
                bl[fn] = *(const short8*)(ldsBlo + off);
            }
            #pragma unroll
            for (int fm = 0; fm < 4; ++fm)
                #pragma unroll
                for (int fn = 0; fn < 4; ++fn) {
                    acc[fm][fn] = __builtin_amdgcn_mfma_f32_16x16x32_bf16(
                        ah[fm], bh[fn], acc[fm][fn], 0, 0, 0);
                    acc[fm][fn] = __builtin_amdgcn_mfma_f32_16x16x32_bf16(
                        ah[fm], bl[fn], acc[fm][fn], 0, 0, 0);
                    acc[fm][fn] = __builtin_amdgcn_mfma_f32_16x16x32_bf16(
                        al[fm], bh[fn], acc[fm][fn], 0, 0, 0);
                }
        }
        __syncthreads();
    }

    // ---- epilogue ----
    float rp[4][4], cp[4];
    #pragma unroll
    for (int a = 0; a < 4; ++a) {
        cp[a] = 0.f;
        #pragma unroll
        for (int b = 0; b < 4; ++b) rp[a][b] = 0.f;
    }
    float* ldsT = reinterpret_cast<float*>(lds);  // 16384 floats, reuse

    #pragma unroll
    for (int fm = 0; fm < 4; ++fm) {
        #pragma unroll
        for (int fn = 0; fn < 4; ++fn) {
            #pragma unroll
            for (int r = 0; r < 4; ++r) {
                float dot = acc[fm][fn][r];
                float sqd = rsq[fm][r] + csq[fn] - 2.0f * dot;
                sqd = fmaxf(sqd, 0.0f);
                float d = sqrtf(sqd);
                int lr = wm * 64 + fm * 16 + lk * 4 + r;   // local row
                int lc = wn * 64 + fn * 16 + l15;          // local col
                out[(size_t)(row0 + lr) * NN + col0 + lc] = d;
                rp[fm][r] += d;
                if (offdiag) {
                    cp[fn] += d;
                    // transposed store T[c][r], XOR-swizzled to <=2-way conflict
                    ldsT[lc * 128 + (lr ^ ((lc & 31) ^ ((lc & 4) << 2)))] = d;
                }
            }
        }
    }

    // row sums -> denom[row0..]
    #pragma unroll
    for (int fm = 0; fm < 4; ++fm)
        #pragma unroll
        for (int r = 0; r < 4; ++r) {
            float v = rp[fm][r];
            v += __shfl_xor(v, 1, 64);
            v += __shfl_xor(v, 2, 64);
            v += __shfl_xor(v, 4, 64);
            v += __shfl_xor(v, 8, 64);
            if (l15 == 0)
                atomicAdd(&denom[row0 + wm * 64 + fm * 16 + lk * 4 + r], v);
        }

    if (offdiag) {
        // col sums -> denom[col0..]
        #pragma unroll
        for (int fn = 0; fn < 4; ++fn) {
            float v = cp[fn];
            v += __shfl_xor(v, 16, 64);
            v += __shfl_xor(v, 32, 64);
            if (lane < 16)
                atomicAdd(&denom[col0 + wn * 64 + fn * 16 + l15], v);
        }
        __syncthreads();
        // mirror-tile write, coalesced reads of swizzled LDS
        #pragma unroll
        for (int it = 0; it < 64; ++it) {
            int idx = it * 256 + tid;
            int c  = idx >> 7;
            int r_ = idx & 127;
            float d = ldsT[c * 128 + (r_ ^ ((c & 31) ^ ((c & 4) << 2)))];
            out[(size_t)(col0 + c) * NN + row0 + r_] = d;
        }
    }
}

// ---------------------------------------------------------------------------
__global__ void inv_kernel(float* __restrict__ denom) {
    int i = blockIdx.x * 256 + threadIdx.x;
    if (i < NN) denom[i] = 1.0f / denom[i];
}

// normalize: 8192 blocks (32/CU), 8 fully-unrolled independent float4 RMWs
__global__ void norm_kernel(float* __restrict__ out,
                            const float* __restrict__ inv) {
    const int i0 = blockIdx.x * blockDim.x + threadIdx.x;  // 0..2M-1
    float4* o4 = reinterpret_cast<float4*>(out);
    #pragma unroll
    for (int k = 0; k < 8; ++k) {
        int idx = k * 2097152 + i0;
        float s = inv[idx >> 11];              // 2048 float4 per row
        float4 v = o4[idx];
        v.x *= s; v.y *= s; v.z *= s; v.w *= s;
        o4[idx] = v;
    }
}

extern "C" void kernel_launch(void* const* d_in, const int* in_sizes, int n_in,
                              void* d_out, int out_size, void* d_ws, size_t ws_size,
                              hipStream_t stream) {
    const float* x = (const float*)d_in[0];
    float* out = (float*)d_out;
    char* ws = (char*)d_ws;
    unsigned short* hi = (unsigned short*)ws;                          // 4 MB
    unsigned short* lo = (unsigned short*)(ws + (size_t)NN * DD * 2);  // 4 MB
    float* sq    = (float*)(ws + (size_t)NN * DD * 4);                 // 32 KB
    float* denom = (float*)(ws + (size_t)NN * DD * 4 + NN * 4);        // 32 KB

    prep_kernel<<<NN, 256, 0, stream>>>(x, hi, lo, sq, denom);
    dist_kernel<<<2080, 256, 0, stream>>>(hi, lo, sq, out, denom);
    inv_kernel<<<32, 256, 0, stream>>>(denom);
    norm_kernel<<<8192, 256, 0, stream>>>(out, denom);
}

// Round 6
// 421.251 us; speedup vs baseline: 1.1398x; 1.0128x over previous
//
#include <hip/hip_runtime.h>
#include <stdint.h>

#define NN 8192
#define DD 256

typedef __attribute__((ext_vector_type(8))) short short8;
typedef __attribute__((ext_vector_type(4))) float f32x4;

typedef const uint32_t __attribute__((address_space(1)))* gbl_ptr_t;
typedef uint32_t __attribute__((address_space(3)))* lds_ptr_t;

__device__ __forceinline__ void gl_lds16(const void* g, const void* l) {
    __builtin_amdgcn_global_load_lds((gbl_ptr_t)(uintptr_t)g,
                                     (lds_ptr_t)(uintptr_t)l, 16, 0, 0);
}

__device__ __forceinline__ unsigned short f32_to_bf16(float f) {
    uint32_t u = __float_as_uint(f);
    u += 0x7fff + ((u >> 16) & 1);   // RNE
    return (unsigned short)(u >> 16);
}
__device__ __forceinline__ float bf16_to_f32(unsigned short h) {
    return __uint_as_float(((uint32_t)h) << 16);
}

// ---------------------------------------------------------------------------
// prep: hi/lo bf16 split stored PRE-SWIZZLED (rule #21: linear LDS dest +
// inverse-swizzled global source + XOR on ds_read), sq[r], denom[r]=0.
// ---------------------------------------------------------------------------
__global__ void prep_kernel(const float* __restrict__ x,
                            unsigned short* __restrict__ hi,
                            unsigned short* __restrict__ lo,
                            float* __restrict__ sq,
                            float* __restrict__ denom) {
    const int r = blockIdx.x;
    const int t = threadIdx.x;                 // 0..255 = column
    float v = x[(size_t)r * DD + t];
    unsigned short h = f32_to_bf16(v);
    unsigned short l = f32_to_bf16(v - bf16_to_f32(h));
    int csw = (t & ~63) | ((((t >> 3) & 7) ^ (r & 7)) << 3) | (t & 7);
    hi[(size_t)r * DD + csw] = h;
    lo[(size_t)r * DD + csw] = l;

    float s = v * v;
    #pragma unroll
    for (int m = 32; m >= 1; m >>= 1) s += __shfl_xor(s, m, 64);
    __shared__ float ws[4];
    if ((t & 63) == 0) ws[t >> 6] = s;
    __syncthreads();
    if (t == 0) {
        sq[r] = ws[0] + ws[1] + ws[2] + ws[3];
        denom[r] = 0.0f;
    }
}

// ---------------------------------------------------------------------------
// dist: UPPER-TRIANGLE tiles (2080 blocks), 128x128 tile, 4 waves 2x2,
// mfma_f32_16x16x32_bf16, split product hh+hl+lh.
// T14 pipeline: single 64KB LDS buffer (2 blocks/CU) + next-kt tile staged
// through registers, written to LDS after the post-MFMA barrier.
// ---------------------------------------------------------------------------
__launch_bounds__(256, 2)
__global__ void dist_kernel(const unsigned short* __restrict__ hi,
                            const unsigned short* __restrict__ lo,
                            const float* __restrict__ sq,
                            float* __restrict__ out,
                            float* __restrict__ denom) {
    __shared__ __align__(16) unsigned short lds[4 * 128 * 64];  // 64 KB
    unsigned short* ldsAhi = lds;
    unsigned short* ldsAlo = lds + 8192;
    unsigned short* ldsBhi = lds + 16384;
    unsigned short* ldsBlo = lds + 24576;

    const int tid  = threadIdx.x;
    const int lane = tid & 63;
    const int wid  = tid >> 6;
    const int wm = wid >> 1, wn = wid & 1;
    const int l15 = lane & 15, lk = lane >> 4;

    // triangular decode: block -> (bi, bj), bj >= bi
    int t = blockIdx.x, bi = 0;
    while (t >= 64 - bi) { t -= 64 - bi; ++bi; }
    const int bj = bi + t;
    const int row0 = bi * 128;
    const int col0 = bj * 128;
    const bool offdiag = (bj > bi);

    f32x4 acc[4][4];
    #pragma unroll
    for (int a = 0; a < 4; ++a)
        #pragma unroll
        for (int b = 0; b < 4; ++b) acc[a][b] = (f32x4){0.f, 0.f, 0.f, 0.f};

    float rsq[4][4], csq[4];
    #pragma unroll
    for (int fm = 0; fm < 4; ++fm)
        #pragma unroll
        for (int r = 0; r < 4; ++r)
            rsq[fm][r] = sq[row0 + wm * 64 + fm * 16 + lk * 4 + r];
    #pragma unroll
    for (int fn = 0; fn < 4; ++fn)
        csq[fn] = sq[col0 + wn * 64 + fn * 16 + l15];

    // per-thread staging geometry (same for gl_lds and manual path)
    // lin = c*256 + tid ; row = lin>>3 ; col8 = lin&7 ; 16B chunk each
    // prologue: stage kt=0 async into LDS
    #pragma unroll
    for (int c = 0; c < 4; ++c) {
        int lin  = c * 256 + tid;
        int row  = lin >> 3;
        int col8 = lin & 7;
        size_t goffA = (size_t)(row0 + row) * DD + col8 * 8;
        size_t goffB = (size_t)(col0 + row) * DD + col8 * 8;
        size_t lbyte = (size_t)(c * 256 + wid * 64) * 16;  // wave-uniform base
        gl_lds16(hi + goffA, (const char*)ldsAhi + lbyte);
        gl_lds16(lo + goffA, (const char*)ldsAlo + lbyte);
        gl_lds16(hi + goffB, (const char*)ldsBhi + lbyte);
        gl_lds16(lo + goffB, (const char*)ldsBlo + lbyte);
    }
    __syncthreads();

    for (int kt = 0; kt < 4; ++kt) {
        // (a) issue next-tile global loads into registers (latency hides
        //     under the MFMA phase below)
        short8 stg[16];
        if (kt < 3) {
            #pragma unroll
            for (int c = 0; c < 4; ++c) {
                int lin  = c * 256 + tid;
                int row  = lin >> 3;
                int col8 = lin & 7;
                size_t goffA = (size_t)(row0 + row) * DD + (kt + 1) * 64 + col8 * 8;
                size_t goffB = (size_t)(col0 + row) * DD + (kt + 1) * 64 + col8 * 8;
                stg[c * 4 + 0] = *(const short8*)(hi + goffA);
                stg[c * 4 + 1] = *(const short8*)(lo + goffA);
                stg[c * 4 + 2] = *(const short8*)(hi + goffB);
                stg[c * 4 + 3] = *(const short8*)(lo + goffB);
            }
        }

        // (b) compute current tile from LDS
        #pragma unroll
        for (int ks = 0; ks < 2; ++ks) {
            short8 ah[4], al[4], bh[4], bl[4];
            #pragma unroll
            for (int fm = 0; fm < 4; ++fm) {
                int row = wm * 64 + fm * 16 + l15;
                int cb  = (ks * 64 + lk * 16) ^ ((row & 7) << 4);  // byte XOR swz
                int off = row * 64 + (cb >> 1);
                ah[fm] = *(const short8*)(ldsAhi + off);
                al[fm] = *(const short8*)(ldsAlo + off);
            }
            #pragma unroll
            for (int fn = 0; fn < 4; ++fn) {
                int row = wn * 64 + fn * 16 + l15;
                int cb  = (ks * 64 + lk * 16) ^ ((row & 7) << 4);
                int off = row * 64 + (cb >> 1);
                bh[fn] = *(const short8*)(ldsBhi + off);
                bl[fn] = *(const short8*)(ldsBlo + off);
            }
            #pragma unroll
            for (int fm = 0; fm < 4; ++fm)
                #pragma unroll
                for (int fn = 0; fn < 4; ++fn) {
                    acc[fm][fn] = __builtin_amdgcn_mfma_f32_16x16x32_bf16(
                        ah[fm], bh[fn], acc[fm][fn], 0, 0, 0);
                    acc[fm][fn] = __builtin_amdgcn_mfma_f32_16x16x32_bf16(
                        ah[fm], bl[fn], acc[fm][fn], 0, 0, 0);
                    acc[fm][fn] = __builtin_amdgcn_mfma_f32_16x16x32_bf16(
                        al[fm], bh[fn], acc[fm][fn], 0, 0, 0);
                }
        }
        __syncthreads();   // all waves done reading LDS

        // (c) reg -> LDS for next tile (linear layout, same image as gl_lds)
        if (kt < 3) {
            #pragma unroll
            for (int c = 0; c < 4; ++c) {
                size_t lbyte = (size_t)(c * 256 + wid * 64 + lane) * 16;
                *(short8*)((char*)ldsAhi + lbyte) = stg[c * 4 + 0];
                *(short8*)((char*)ldsAlo + lbyte) = stg[c * 4 + 1];
                *(short8*)((char*)ldsBhi + lbyte) = stg[c * 4 + 2];
                *(short8*)((char*)ldsBlo + lbyte) = stg[c * 4 + 3];
            }
            __syncthreads();
        }
    }

    // ---- epilogue ----
    float rp[4][4], cp[4];
    #pragma unroll
    for (int a = 0; a < 4; ++a) {
        cp[a] = 0.f;
        #pragma unroll
        for (int b = 0; b < 4; ++b) rp[a][b] = 0.f;
    }
    float* ldsT = reinterpret_cast<float*>(lds);  // 16384 floats, reuse

    #pragma unroll
    for (int fm = 0; fm < 4; ++fm) {
        #pragma unroll
        for (int fn = 0; fn < 4; ++fn) {
            #pragma unroll
            for (int r = 0; r < 4; ++r) {
                float dot = acc[fm][fn][r];
                float sqd = rsq[fm][r] + csq[fn] - 2.0f * dot;
                sqd = fmaxf(sqd, 0.0f);
                float d = sqrtf(sqd);
                int lr = wm * 64 + fm * 16 + lk * 4 + r;   // local row
                int lc = wn * 64 + fn * 16 + l15;          // local col
                out[(size_t)(row0 + lr) * NN + col0 + lc] = d;
                rp[fm][r] += d;
                if (offdiag) {
                    cp[fn] += d;
                    // transposed store T[c][r], XOR-swizzled (<=2-way banks)
                    ldsT[lc * 128 + (lr ^ ((lc & 31) ^ ((lc & 4) << 2)))] = d;
                }
            }
        }
    }

    // row sums -> denom[row0..]
    #pragma unroll
    for (int fm = 0; fm < 4; ++fm)
        #pragma unroll
        for (int r = 0; r < 4; ++r) {
            float v = rp[fm][r];
            v += __shfl_xor(v, 1, 64);
            v += __shfl_xor(v, 2, 64);
            v += __shfl_xor(v, 4, 64);
            v += __shfl_xor(v, 8, 64);
            if (l15 == 0)
                atomicAdd(&denom[row0 + wm * 64 + fm * 16 + lk * 4 + r], v);
        }

    if (offdiag) {
        // col sums -> denom[col0..]
        #pragma unroll
        for (int fn = 0; fn < 4; ++fn) {
            float v = cp[fn];
            v += __shfl_xor(v, 16, 64);
            v += __shfl_xor(v, 32, 64);
            if (lane < 16)
                atomicAdd(&denom[col0 + wn * 64 + fn * 16 + l15], v);
        }
        __syncthreads();
        // mirror-tile write, coalesced reads of swizzled LDS
        #pragma unroll
        for (int it = 0; it < 64; ++it) {
            int idx = it * 256 + tid;
            int c  = idx >> 7;
            int r_ = idx & 127;
            float d = ldsT[c * 128 + (r_ ^ ((c & 31) ^ ((c & 4) << 2)))];
            out[(size_t)(col0 + c) * NN + row0 + r_] = d;
        }
    }
}

// ---------------------------------------------------------------------------
// normalize: one block per row; denom broadcast once; 8 independent float4
// RMWs per thread, fully unrolled (ILP 8).  inv_kernel folded in here.
// ---------------------------------------------------------------------------
__global__ void norm_kernel(float* __restrict__ out,
                            const float* __restrict__ denom) {
    const int r = blockIdx.x;
    const float inv = 1.0f / denom[r];        // HW-broadcast load, 1 divide
    float4* o4 = reinterpret_cast<float4*>(out) + (size_t)r * 2048;
    #pragma unroll
    for (int k = 0; k < 8; ++k) {
        float4 v = o4[k * 256 + threadIdx.x];
        v.x *= inv; v.y *= inv; v.z *= inv; v.w *= inv;
        o4[k * 256 + threadIdx.x] = v;
    }
}

extern "C" void kernel_launch(void* const* d_in, const int* in_sizes, int n_in,
                              void* d_out, int out_size, void* d_ws, size_t ws_size,
                              hipStream_t stream) {
    const float* x = (const float*)d_in[0];
    float* out = (float*)d_out;
    char* ws = (char*)d_ws;
    unsigned short* hi = (unsigned short*)ws;                          // 4 MB
    unsigned short* lo = (unsigned short*)(ws + (size_t)NN * DD * 2);  // 4 MB
    float* sq    = (float*)(ws + (size_t)NN * DD * 4);                 // 32 KB
    float* denom = (float*)(ws + (size_t)NN * DD * 4 + NN * 4);        // 32 KB

    prep_kernel<<<NN, 256, 0, stream>>>(x, hi, lo, sq, denom);
    dist_kernel<<<2080, 256, 0, stream>>>(hi, lo, sq, out, denom);
    norm_kernel<<<NN, 256, 0, stream>>>(out, denom);
}